// Round 1
// baseline (6026.258 us; speedup 1.0000x reference)
//
#include <hip/hip_runtime.h>
#include <math.h>

// Problem constants
#define BB 4
#define SS 1024
#define DD 2048
#define HH 16
#define DKK 128
#define KKTOP 307           // int(1024 * 0.3)
#define MROWS (BB * SS)     // 4096
static __device__ __constant__ float SCALE = 0.08838834764831845f; // 1/sqrt(128)

// ---------------------------------------------------------------------------
// GEMM: C[M,N] = A[M,K] @ W[N,K]^T + bias[N]   (torch Linear)
// fp32, 128x128 tile, BK=32, 256 threads, 8x8 per thread.
// LDS stores tiles transposed [BK][TM] so fragment reads are float4.
// ---------------------------------------------------------------------------
#define TM 128
#define TN 128
#define TK 32
#define LDP (TM + 4)   // pad keeps float4 alignment (4-float pad) + spreads banks

__global__ __launch_bounds__(256) void gemm_nt_f32(
    const float* __restrict__ A, const float* __restrict__ W,
    const float* __restrict__ bias, float* __restrict__ C,
    int M, int N, int K)
{
    __shared__ float As[TK][LDP];
    __shared__ float Ws[TK][LDP];

    const int tid = threadIdx.x;
    const int bm = blockIdx.x * TM;
    const int bn = blockIdx.y * TN;
    const int tx = tid & 15;        // 0..15 -> col group
    const int ty = tid >> 4;        // 0..15 -> row group

    const int lr = tid >> 3;        // 0..31 loader row
    const int lk = (tid & 7) << 2;  // 0,4,...,28 loader k

    float acc[8][8];
    #pragma unroll
    for (int i = 0; i < 8; ++i)
        #pragma unroll
        for (int j = 0; j < 8; ++j) acc[i][j] = 0.f;

    for (int kt = 0; kt < K; kt += TK) {
        __syncthreads();  // protect LDS before overwrite
        const float* Ag = A + (size_t)(bm + lr) * K + kt + lk;
        const float* Wg = W + (size_t)(bn + lr) * K + kt + lk;
        #pragma unroll
        for (int m = 0; m < 4; ++m) {
            float4 av = *(const float4*)(Ag + (size_t)m * 32 * K);
            float4 wv = *(const float4*)(Wg + (size_t)m * 32 * K);
            int r = lr + m * 32;
            As[lk + 0][r] = av.x; As[lk + 1][r] = av.y;
            As[lk + 2][r] = av.z; As[lk + 3][r] = av.w;
            Ws[lk + 0][r] = wv.x; Ws[lk + 1][r] = wv.y;
            Ws[lk + 2][r] = wv.z; Ws[lk + 3][r] = wv.w;
        }
        __syncthreads();

        #pragma unroll
        for (int k = 0; k < TK; ++k) {
            float a[8], w[8];
            *(float4*)&a[0] = *(const float4*)&As[k][ty * 8];
            *(float4*)&a[4] = *(const float4*)&As[k][ty * 8 + 4];
            *(float4*)&w[0] = *(const float4*)&Ws[k][tx * 8];
            *(float4*)&w[4] = *(const float4*)&Ws[k][tx * 8 + 4];
            #pragma unroll
            for (int i = 0; i < 8; ++i)
                #pragma unroll
                for (int j = 0; j < 8; ++j)
                    acc[i][j] += a[i] * w[j];
        }
    }

    float bv[8];
    *(float4*)&bv[0] = *(const float4*)&bias[bn + tx * 8];
    *(float4*)&bv[4] = *(const float4*)&bias[bn + tx * 8 + 4];

    #pragma unroll
    for (int i = 0; i < 8; ++i) {
        float* cp = C + (size_t)(bm + ty * 8 + i) * N + bn + tx * 8;
        float4 o0 = make_float4(acc[i][0] + bv[0], acc[i][1] + bv[1],
                                acc[i][2] + bv[2], acc[i][3] + bv[3]);
        float4 o1 = make_float4(acc[i][4] + bv[4], acc[i][5] + bv[5],
                                acc[i][6] + bv[6], acc[i][7] + bv[7]);
        *(float4*)cp = o0;
        *(float4*)(cp + 4) = o1;
    }
}

// ---------------------------------------------------------------------------
// Fused scores -> top-k(307) -> softmax -> attn write -> PV.
// One block = 4 query rows of one (b,h). 256 threads = 4 waves.
// Wave w owns query row w for sort/softmax (row confined to one wave ->
// no __syncthreads needed inside the bitonic sort).
// ---------------------------------------------------------------------------
__global__ __launch_bounds__(256) void attn_topk_fused(
    const float* __restrict__ Q, const float* __restrict__ Kp,
    const float* __restrict__ V, float* __restrict__ attn_out,
    float* __restrict__ CTX)
{
    const int tid = threadIdx.x;
    const int b = blockIdx.z;
    const int h = blockIdx.y;
    const int q0 = blockIdx.x * 4;

    __shared__ float qs[4][DKK];        // 2 KB
    __shared__ float sc[4][SS];         // 16 KB  original scores
    __shared__ float wbuf[4][SS];       // 16 KB  sort buffer, then weights
    __shared__ float part[2][4][DKK];   // 4 KB   PV partial sums

    // --- load 4 q rows ---
    for (int i = tid; i < 4 * DKK; i += 256) {
        int r = i >> 7, c = i & (DKK - 1);
        qs[r][c] = Q[(size_t)(b * SS + q0 + r) * DD + h * DKK + c];
    }
    __syncthreads();

    // --- scores: thread t -> keys t, t+256, t+512, t+768, all 4 rows ---
    {
        const float* kb = Kp + (size_t)b * SS * DD + h * DKK;
        const int j0 = tid;
        float acc[4][4];
        #pragma unroll
        for (int r = 0; r < 4; ++r)
            #pragma unroll
            for (int j = 0; j < 4; ++j) acc[r][j] = 0.f;

        for (int c = 0; c < DKK; c += 4) {
            float4 k0 = *(const float4*)(kb + (size_t)(j0)       * DD + c);
            float4 k1 = *(const float4*)(kb + (size_t)(j0 + 256) * DD + c);
            float4 k2 = *(const float4*)(kb + (size_t)(j0 + 512) * DD + c);
            float4 k3 = *(const float4*)(kb + (size_t)(j0 + 768) * DD + c);
            #pragma unroll
            for (int r = 0; r < 4; ++r) {
                float4 qv = *(const float4*)&qs[r][c];
                acc[r][0] += qv.x * k0.x + qv.y * k0.y + qv.z * k0.z + qv.w * k0.w;
                acc[r][1] += qv.x * k1.x + qv.y * k1.y + qv.z * k1.z + qv.w * k1.w;
                acc[r][2] += qv.x * k2.x + qv.y * k2.y + qv.z * k2.z + qv.w * k2.w;
                acc[r][3] += qv.x * k3.x + qv.y * k3.y + qv.z * k3.z + qv.w * k3.w;
            }
        }
        #pragma unroll
        for (int r = 0; r < 4; ++r) {
            sc[r][j0]       = acc[r][0] * SCALE;
            sc[r][j0 + 256] = acc[r][1] * SCALE;
            sc[r][j0 + 512] = acc[r][2] * SCALE;
            sc[r][j0 + 768] = acc[r][3] * SCALE;
        }
    }
    __syncthreads();

    // --- copy scores into sort buffer ---
    for (int i = tid; i < 4 * SS; i += 256)
        ((float*)wbuf)[i] = ((const float*)sc)[i];
    __syncthreads();

    const int row = tid >> 6;   // wave id = query row
    const int lane = tid & 63;

    // --- bitonic sort (ascending), each wave sorts its own row ---
    for (int k = 2; k <= SS; k <<= 1) {
        for (int j = k >> 1; j > 0; j >>= 1) {
            for (int i = lane; i < SS; i += 64) {
                int ixj = i ^ j;
                if (ixj > i) {
                    float a = wbuf[row][i];
                    float c2 = wbuf[row][ixj];
                    bool sw = ((i & k) == 0) ? (a > c2) : (a < c2);
                    if (sw) { wbuf[row][i] = c2; wbuf[row][ixj] = a; }
                }
            }
        }
    }

    const float tval = wbuf[row][SS - KKTOP];  // 307th largest
    const float mval = wbuf[row][SS - 1];      // max

    // --- g = #{s > t}, se = sum exp(s - m) over s > t (wave reduce) ---
    int g = 0; float se = 0.f;
    for (int i = lane; i < SS; i += 64) {
        float s = sc[row][i];
        if (s > tval) { g += 1; se += expf(s - mval); }
    }
    #pragma unroll
    for (int o = 32; o > 0; o >>= 1) {
        g += __shfl_down(g, o);
        se += __shfl_down(se, o);
    }
    g = __shfl(g, 0);
    se = __shfl(se, 0);
    const int e = KKTOP - g;                 // # ties at t to include (>=1)
    const float expt = expf(tval - mval);
    const float Z = se + (float)e * expt;
    const float inv = 1.0f / Z;

    // --- weights + global attn write ---
    {
        float* ao = attn_out + ((size_t)((b * HH + h) * SS + q0 + row)) * SS;
        for (int i = lane; i < SS; i += 64) {
            float s = sc[row][i];
            float w;
            if (s > tval) {
                w = expf(s - mval) * inv;
            } else if (s == tval) {
                int rank = 0;                 // ties broken by lowest index
                for (int j2 = 0; j2 < i; ++j2) rank += (sc[row][j2] == tval);
                w = (rank < e) ? expt * inv : 0.f;
            } else {
                w = 0.f;
            }
            wbuf[row][i] = w;
            ao[i] = w;
        }
    }
    __syncthreads();

    // --- PV: ctx[r][c] = sum_j w[r][j] * V[b,j,h,c] ---
    {
        const int half = tid >> 7;          // 0/1 -> key halves
        const int c = tid & 127;
        const int jb = half << 9;
        const float* vb = V + (size_t)b * SS * DD + h * DKK + c + (size_t)jb * DD;
        float a0 = 0.f, a1 = 0.f, a2 = 0.f, a3 = 0.f;
        for (int j = 0; j < 512; ++j) {
            float w0 = wbuf[0][jb + j];
            float w1 = wbuf[1][jb + j];
            float w2 = wbuf[2][jb + j];
            float w3 = wbuf[3][jb + j];
            if (w0 == 0.f && w1 == 0.f && w2 == 0.f && w3 == 0.f) continue;
            float v = vb[(size_t)j * DD];
            a0 += w0 * v; a1 += w1 * v; a2 += w2 * v; a3 += w3 * v;
        }
        part[half][0][c] = a0; part[half][1][c] = a1;
        part[half][2][c] = a2; part[half][3][c] = a3;
    }
    __syncthreads();
    if (tid < 128) {
        const int c = tid;
        float* cb = CTX + (size_t)(b * SS + q0) * DD + h * DKK + c;
        #pragma unroll
        for (int r = 0; r < 4; ++r)
            cb[(size_t)r * DD] = part[0][r][c] + part[1][r][c];
    }
}

// ---------------------------------------------------------------------------
extern "C" void kernel_launch(void* const* d_in, const int* in_sizes, int n_in,
                              void* d_out, int out_size, void* d_ws, size_t ws_size,
                              hipStream_t stream)
{
    const float* x  = (const float*)d_in[0];
    const float* Wq = (const float*)d_in[1];
    const float* bq = (const float*)d_in[2];
    const float* Wk = (const float*)d_in[3];
    const float* bk = (const float*)d_in[4];
    const float* Wv = (const float*)d_in[5];
    const float* bv = (const float*)d_in[6];
    const float* Wo = (const float*)d_in[7];
    const float* bo = (const float*)d_in[8];

    float* out      = (float*)d_out;                       // [4,1024,2048]
    float* attn_out = (float*)d_out + (size_t)MROWS * DD;  // [4,16,1024,1024]

    float* ws = (float*)d_ws;
    const size_t PLANE = (size_t)MROWS * DD;   // 8,388,608 floats
    float* Qb  = ws;
    float* Kb  = ws + PLANE;
    float* Vb  = ws + 2 * PLANE;
    float* CTX = ws + 3 * PLANE;

    dim3 gb(MROWS / TM, DD / TN);   // (32,16)
    gemm_nt_f32<<<gb, 256, 0, stream>>>(x, Wq, bq, Qb, MROWS, DD, DD);
    gemm_nt_f32<<<gb, 256, 0, stream>>>(x, Wk, bk, Kb, MROWS, DD, DD);
    gemm_nt_f32<<<gb, 256, 0, stream>>>(x, Wv, bv, Vb, MROWS, DD, DD);

    attn_topk_fused<<<dim3(SS / 4, HH, BB), 256, 0, stream>>>(
        Qb, Kb, Vb, attn_out, CTX);

    gemm_nt_f32<<<gb, 256, 0, stream>>>(CTX, Wo, bo, out, MROWS, DD, DD);
}

// Round 3
// 4572.857 us; speedup vs baseline: 1.3178x; 1.3178x over previous
//
#include <hip/hip_runtime.h>
#include <math.h>

// Problem constants
#define BB 4
#define SS 1024
#define DD 2048
#define HH 16
#define DKK 128
#define KKTOP 307           // int(1024 * 0.3)
#define MROWS (BB * SS)     // 4096
static __device__ __constant__ float SCALE = 0.08838834764831845f; // 1/sqrt(128)

// ---------------------------------------------------------------------------
// GEMM: C[M,N] = A[M,K] @ W[N,K]^T + bias[N]   (torch Linear)
// fp32, 128x128 tile, BK=32, 256 threads, 8x8 per thread.  (round-1 verified)
// ---------------------------------------------------------------------------
#define TM 128
#define TN 128
#define TK 32
#define LDP (TM + 4)

__global__ __launch_bounds__(256) void gemm_nt_f32(
    const float* __restrict__ A, const float* __restrict__ W,
    const float* __restrict__ bias, float* __restrict__ C,
    int M, int N, int K)
{
    __shared__ float As[TK][LDP];
    __shared__ float Ws[TK][LDP];

    const int tid = threadIdx.x;
    const int bm = blockIdx.x * TM;
    const int bn = blockIdx.y * TN;
    const int tx = tid & 15;
    const int ty = tid >> 4;

    const int lr = tid >> 3;
    const int lk = (tid & 7) << 2;

    float acc[8][8];
    #pragma unroll
    for (int i = 0; i < 8; ++i)
        #pragma unroll
        for (int j = 0; j < 8; ++j) acc[i][j] = 0.f;

    for (int kt = 0; kt < K; kt += TK) {
        __syncthreads();
        const float* Ag = A + (size_t)(bm + lr) * K + kt + lk;
        const float* Wg = W + (size_t)(bn + lr) * K + kt + lk;
        #pragma unroll
        for (int m = 0; m < 4; ++m) {
            float4 av = *(const float4*)(Ag + (size_t)m * 32 * K);
            float4 wv = *(const float4*)(Wg + (size_t)m * 32 * K);
            int r = lr + m * 32;
            As[lk + 0][r] = av.x; As[lk + 1][r] = av.y;
            As[lk + 2][r] = av.z; As[lk + 3][r] = av.w;
            Ws[lk + 0][r] = wv.x; Ws[lk + 1][r] = wv.y;
            Ws[lk + 2][r] = wv.z; Ws[lk + 3][r] = wv.w;
        }
        __syncthreads();

        #pragma unroll
        for (int k = 0; k < TK; ++k) {
            float a[8], w[8];
            *(float4*)&a[0] = *(const float4*)&As[k][ty * 8];
            *(float4*)&a[4] = *(const float4*)&As[k][ty * 8 + 4];
            *(float4*)&w[0] = *(const float4*)&Ws[k][tx * 8];
            *(float4*)&w[4] = *(const float4*)&Ws[k][tx * 8 + 4];
            #pragma unroll
            for (int i = 0; i < 8; ++i)
                #pragma unroll
                for (int j = 0; j < 8; ++j)
                    acc[i][j] += a[i] * w[j];
        }
    }

    float bv[8];
    *(float4*)&bv[0] = *(const float4*)&bias[bn + tx * 8];
    *(float4*)&bv[4] = *(const float4*)&bias[bn + tx * 8 + 4];

    #pragma unroll
    for (int i = 0; i < 8; ++i) {
        float* cp = C + (size_t)(bm + ty * 8 + i) * N + bn + tx * 8;
        float4 o0 = make_float4(acc[i][0] + bv[0], acc[i][1] + bv[1],
                                acc[i][2] + bv[2], acc[i][3] + bv[3]);
        float4 o1 = make_float4(acc[i][4] + bv[4], acc[i][5] + bv[5],
                                acc[i][6] + bv[6], acc[i][7] + bv[7]);
        *(float4*)cp = o0;
        *(float4*)(cp + 4) = o1;
    }
}

// ---------------------------------------------------------------------------
// Fused scores -> ballot bit-descent top-k(307) -> softmax -> attn write -> PV.
// One block = 4 query rows of one (b,h). 256 threads = 4 waves; wave w owns
// query row w. Selection keeps the row in REGISTERS (16 uints/lane); the only
// cross-lane primitive is __ballot (SGPR-uniform result, no broadcast needed).
// ---------------------------------------------------------------------------
__device__ __forceinline__ unsigned f2u_ord(float f) {
    unsigned x = __float_as_uint(f);
    return (x & 0x80000000u) ? ~x : (x | 0x80000000u);
}
__device__ __forceinline__ float u2f_ord(unsigned u) {
    return __uint_as_float((u & 0x80000000u) ? (u & 0x7fffffffu) : ~u);
}

__global__ __launch_bounds__(256) void attn_topk_fused(
    const float* __restrict__ Q, const float* __restrict__ Kp,
    const float* __restrict__ V, float* __restrict__ attn_out,
    float* __restrict__ CTX)
{
    const int tid = threadIdx.x;
    const int b = blockIdx.z;
    const int h = blockIdx.y;
    const int q0 = blockIdx.x * 4;

    __shared__ float qs[4][DKK];          // 2 KB
    __shared__ float sc[4][SS];           // 16 KB  scores, later weights (in place)
    __shared__ float part[2][4][DKK];     // 4 KB   PV partial sums

    // --- load 4 q rows ---
    for (int i = tid; i < 4 * DKK; i += 256) {
        int r = i >> 7, c = i & (DKK - 1);
        qs[r][c] = Q[(size_t)(b * SS + q0 + r) * DD + h * DKK + c];
    }
    __syncthreads();

    // --- scores: thread t -> keys t, t+256, t+512, t+768, all 4 rows ---
    {
        const float* kb = Kp + (size_t)b * SS * DD + h * DKK;
        const int j0 = tid;
        float acc[4][4];
        #pragma unroll
        for (int r = 0; r < 4; ++r)
            #pragma unroll
            for (int j = 0; j < 4; ++j) acc[r][j] = 0.f;

        for (int c = 0; c < DKK; c += 4) {
            float4 k0 = *(const float4*)(kb + (size_t)(j0)       * DD + c);
            float4 k1 = *(const float4*)(kb + (size_t)(j0 + 256) * DD + c);
            float4 k2 = *(const float4*)(kb + (size_t)(j0 + 512) * DD + c);
            float4 k3 = *(const float4*)(kb + (size_t)(j0 + 768) * DD + c);
            #pragma unroll
            for (int r = 0; r < 4; ++r) {
                float4 qv = *(const float4*)&qs[r][c];
                acc[r][0] += qv.x * k0.x + qv.y * k0.y + qv.z * k0.z + qv.w * k0.w;
                acc[r][1] += qv.x * k1.x + qv.y * k1.y + qv.z * k1.z + qv.w * k1.w;
                acc[r][2] += qv.x * k2.x + qv.y * k2.y + qv.z * k2.z + qv.w * k2.w;
                acc[r][3] += qv.x * k3.x + qv.y * k3.y + qv.z * k3.z + qv.w * k3.w;
            }
        }
        #pragma unroll
        for (int r = 0; r < 4; ++r) {
            sc[r][j0]       = acc[r][0] * SCALE;
            sc[r][j0 + 256] = acc[r][1] * SCALE;
            sc[r][j0 + 512] = acc[r][2] * SCALE;
            sc[r][j0 + 768] = acc[r][3] * SCALE;
        }
    }
    __syncthreads();

    const int row = tid >> 6;   // wave id = query row
    const int lane = tid & 63;

    // --- pull this row into registers as sortable uints (all unrolled) ---
    unsigned uv[16];
    #pragma unroll
    for (int s2 = 0; s2 < 16; ++s2)
        uv[s2] = f2u_ord(sc[row][s2 * 64 + lane]);

    // --- bit-descent kth-largest: pref = exact uint of 307th-largest score.
    // cnt(u >= cand) is wave-uniform via ballot; no LDS, no shuffles.
    unsigned pref = 0;
    for (int bit = 31; bit >= 0; --bit) {
        unsigned cand = pref | (1u << bit);
        int cnt = 0;
        #pragma unroll
        for (int s2 = 0; s2 < 16; ++s2)
            cnt += __popcll(__ballot(uv[s2] >= cand));
        if (cnt >= KKTOP) pref = cand;
    }
    int g = 0;
    #pragma unroll
    for (int s2 = 0; s2 < 16; ++s2)
        g += __popcll(__ballot(uv[s2] > pref));
    const int e = KKTOP - g;            // #ties at threshold to include (>=1)

    // --- row max (uint order == float order) ---
    unsigned um = 0;
    #pragma unroll
    for (int s2 = 0; s2 < 16; ++s2) um = um > uv[s2] ? um : uv[s2];
    #pragma unroll
    for (int o = 32; o > 0; o >>= 1) {
        unsigned t = __shfl_down(um, o);
        um = um > t ? um : t;
    }
    um = __shfl(um, 0);
    const float m = u2f_ord(um);

    // --- sum of exp over strictly-above-threshold ---
    float se = 0.f;
    #pragma unroll
    for (int s2 = 0; s2 < 16; ++s2) {
        if (uv[s2] > pref) se += expf(u2f_ord(uv[s2]) - m);
    }
    #pragma unroll
    for (int o = 32; o > 0; o >>= 1) se += __shfl_down(se, o);
    se = __shfl(se, 0);

    const float tvalexp = expf(u2f_ord(pref) - m);
    const float inv = 1.0f / (se + (float)e * tvalexp);

    // --- weights from registers; write LDS (for PV) + global attn.
    // Tie ranks in index order via ballot (i = step*64+lane is lexicographic).
    {
        float* ao = attn_out + ((size_t)((b * HH + h) * SS + q0 + row)) * SS;
        int tiesbefore = 0;
        #pragma unroll
        for (int step = 0; step < 16; ++step) {
            const int i = step * 64 + lane;
            const unsigned u = uv[step];
            const bool eq = (u == pref);
            unsigned long long mask = __ballot(eq);
            float w;
            if (u > pref) {
                w = expf(u2f_ord(u) - m) * inv;
            } else if (eq) {
                int rank = tiesbefore +
                    __popcll(mask & ((1ull << lane) - 1ull));
                w = (rank < e) ? tvalexp * inv : 0.f;
            } else {
                w = 0.f;
            }
            sc[row][i] = w;
            ao[i] = w;
            tiesbefore += __popcll(mask);
        }
    }
    __syncthreads();   // all rows' weights final before PV

    // --- PV: ctx[r][c] = sum_j w[r][j] * V[b,j,h,c] ---
    {
        const int half = tid >> 7;
        const int c = tid & 127;
        const int jb = half << 9;
        const float* vb = V + (size_t)b * SS * DD + h * DKK + c + (size_t)jb * DD;
        float a0 = 0.f, a1 = 0.f, a2 = 0.f, a3 = 0.f;
        for (int j = 0; j < 512; ++j) {
            float w0 = sc[0][jb + j];
            float w1 = sc[1][jb + j];
            float w2 = sc[2][jb + j];
            float w3 = sc[3][jb + j];
            if (w0 == 0.f && w1 == 0.f && w2 == 0.f && w3 == 0.f) continue;
            float v = vb[(size_t)j * DD];
            a0 += w0 * v; a1 += w1 * v; a2 += w2 * v; a3 += w3 * v;
        }
        part[half][0][c] = a0; part[half][1][c] = a1;
        part[half][2][c] = a2; part[half][3][c] = a3;
    }
    __syncthreads();
    if (tid < 128) {
        const int c = tid;
        float* cb = CTX + (size_t)(b * SS + q0) * DD + h * DKK + c;
        #pragma unroll
        for (int r = 0; r < 4; ++r)
            cb[(size_t)r * DD] = part[0][r][c] + part[1][r][c];
    }
}

// ---------------------------------------------------------------------------
extern "C" void kernel_launch(void* const* d_in, const int* in_sizes, int n_in,
                              void* d_out, int out_size, void* d_ws, size_t ws_size,
                              hipStream_t stream)
{
    const float* x  = (const float*)d_in[0];
    const float* Wq = (const float*)d_in[1];
    const float* bq = (const float*)d_in[2];
    const float* Wk = (const float*)d_in[3];
    const float* bk = (const float*)d_in[4];
    const float* Wv = (const float*)d_in[5];
    const float* bv = (const float*)d_in[6];
    const float* Wo = (const float*)d_in[7];
    const float* bo = (const float*)d_in[8];

    float* out      = (float*)d_out;                       // [4,1024,2048]
    float* attn_out = (float*)d_out + (size_t)MROWS * DD;  // [4,16,1024,1024]

    float* ws = (float*)d_ws;
    const size_t PLANE = (size_t)MROWS * DD;
    float* Qb  = ws;
    float* Kb  = ws + PLANE;
    float* Vb  = ws + 2 * PLANE;
    float* CTX = ws + 3 * PLANE;

    dim3 gb(MROWS / TM, DD / TN);
    gemm_nt_f32<<<gb, 256, 0, stream>>>(x, Wq, bq, Qb, MROWS, DD, DD);
    gemm_nt_f32<<<gb, 256, 0, stream>>>(x, Wk, bk, Kb, MROWS, DD, DD);
    gemm_nt_f32<<<gb, 256, 0, stream>>>(x, Wv, bv, Vb, MROWS, DD, DD);

    attn_topk_fused<<<dim3(SS / 4, HH, BB), 256, 0, stream>>>(
        Qb, Kb, Vb, attn_out, CTX);

    gemm_nt_f32<<<gb, 256, 0, stream>>>(CTX, Wo, bo, out, MROWS, DD, DD);
}

// Round 4
// 3595.939 us; speedup vs baseline: 1.6759x; 1.2717x over previous
//
#include <hip/hip_runtime.h>
#include <math.h>

// Problem constants
#define BB 4
#define SS 1024
#define DD 2048
#define HH 16
#define DKK 128
#define KKTOP 307           // int(1024 * 0.3)
#define MROWS (BB * SS)     // 4096
static __device__ __constant__ float SCALE = 0.08838834764831845f; // 1/sqrt(128)

// ---------------------------------------------------------------------------
// GEMM: C[M,N] = A[M,K] @ W[N,K]^T + bias[N]   (round-1 verified, unchanged)
// ---------------------------------------------------------------------------
#define TM 128
#define TN 128
#define TK 32
#define LDP (TM + 4)

__global__ __launch_bounds__(256) void gemm_nt_f32(
    const float* __restrict__ A, const float* __restrict__ W,
    const float* __restrict__ bias, float* __restrict__ C,
    int M, int N, int K)
{
    __shared__ float As[TK][LDP];
    __shared__ float Ws[TK][LDP];

    const int tid = threadIdx.x;
    const int bm = blockIdx.x * TM;
    const int bn = blockIdx.y * TN;
    const int tx = tid & 15;
    const int ty = tid >> 4;

    const int lr = tid >> 3;
    const int lk = (tid & 7) << 2;

    float acc[8][8];
    #pragma unroll
    for (int i = 0; i < 8; ++i)
        #pragma unroll
        for (int j = 0; j < 8; ++j) acc[i][j] = 0.f;

    for (int kt = 0; kt < K; kt += TK) {
        __syncthreads();
        const float* Ag = A + (size_t)(bm + lr) * K + kt + lk;
        const float* Wg = W + (size_t)(bn + lr) * K + kt + lk;
        #pragma unroll
        for (int m = 0; m < 4; ++m) {
            float4 av = *(const float4*)(Ag + (size_t)m * 32 * K);
            float4 wv = *(const float4*)(Wg + (size_t)m * 32 * K);
            int r = lr + m * 32;
            As[lk + 0][r] = av.x; As[lk + 1][r] = av.y;
            As[lk + 2][r] = av.z; As[lk + 3][r] = av.w;
            Ws[lk + 0][r] = wv.x; Ws[lk + 1][r] = wv.y;
            Ws[lk + 2][r] = wv.z; Ws[lk + 3][r] = wv.w;
        }
        __syncthreads();

        #pragma unroll
        for (int k = 0; k < TK; ++k) {
            float a[8], w[8];
            *(float4*)&a[0] = *(const float4*)&As[k][ty * 8];
            *(float4*)&a[4] = *(const float4*)&As[k][ty * 8 + 4];
            *(float4*)&w[0] = *(const float4*)&Ws[k][tx * 8];
            *(float4*)&w[4] = *(const float4*)&Ws[k][tx * 8 + 4];
            #pragma unroll
            for (int i = 0; i < 8; ++i)
                #pragma unroll
                for (int j = 0; j < 8; ++j)
                    acc[i][j] += a[i] * w[j];
        }
    }

    float bv[8];
    *(float4*)&bv[0] = *(const float4*)&bias[bn + tx * 8];
    *(float4*)&bv[4] = *(const float4*)&bias[bn + tx * 8 + 4];

    #pragma unroll
    for (int i = 0; i < 8; ++i) {
        float* cp = C + (size_t)(bm + ty * 8 + i) * N + bn + tx * 8;
        float4 o0 = make_float4(acc[i][0] + bv[0], acc[i][1] + bv[1],
                                acc[i][2] + bv[2], acc[i][3] + bv[3]);
        float4 o1 = make_float4(acc[i][4] + bv[4], acc[i][5] + bv[5],
                                acc[i][6] + bv[6], acc[i][7] + bv[7]);
        *(float4*)cp = o0;
        *(float4*)(cp + 4) = o1;
    }
}

// ---------------------------------------------------------------------------
// Fused attn, GEMM-style blocking.
// Block = 32 q-rows of one (b,h); 512 threads = 8 waves; wave w owns rows
// 4w..4w+3. K/V staged in LDS coalesced; lane l computes key t*64+l, so
// score tiles land directly in the verified uv[r][t] register layout.
// Selection = round-3-verified ballot bit-descent (ported verbatim).
// ---------------------------------------------------------------------------
#define QB 32
#define KT2 64
#define NT 16              // SS / KT2
#define LDQ 132            // padded row stride (floats); 132*4 B, 16B-aligned
#define QS_OFF 0           // qs [32][132]  (scores); reused as wtile [32][64] in PV
#define KT_OFF (QB * LDQ)  // ktile [64][132] (scores); reused as vtile in PV
#define LDS_FLOATS (KT_OFF + KT2 * LDQ)   // 12672 floats = 50688 B

__device__ __forceinline__ unsigned f2u_ord(float f) {
    unsigned x = __float_as_uint(f);
    return (x & 0x80000000u) ? ~x : (x | 0x80000000u);
}
__device__ __forceinline__ float u2f_ord(unsigned u) {
    return __uint_as_float((u & 0x80000000u) ? (u & 0x7fffffffu) : ~u);
}

__global__ __launch_bounds__(512) void attn_topk_fused(
    const float* __restrict__ Q, const float* __restrict__ Kp,
    const float* __restrict__ V, float* __restrict__ attn_out,
    float* __restrict__ CTX)
{
    __shared__ float lds[LDS_FLOATS];
    float* qs = lds + QS_OFF;
    float* kt = lds + KT_OFF;

    const int tid = threadIdx.x;
    const int b = blockIdx.z;
    const int h = blockIdx.y;
    const int q0 = blockIdx.x * QB;
    const int wv = tid >> 6;
    const int lane = tid & 63;

    // --- stage Q tile [32][128], coalesced (1024B per wave-instruction) ---
    {
        const float* Qg = Q + (size_t)(b * SS + q0) * DD + h * DKK;
        #pragma unroll
        for (int it = 0; it < 2; ++it) {
            int r = it * 16 + (tid >> 5);
            int c = (tid & 31) * 4;
            *(float4*)&qs[r * LDQ + c] = *(const float4*)(Qg + (size_t)r * DD + c);
        }
    }

    unsigned uv[4][NT];    // wave's 4 rows x 16 tiles (key = t*64 + lane)

    // --- scores: tiled over keys, K-tile in LDS ---
    {
        const float* Kg = Kp + (size_t)b * SS * DD + h * DKK;
        for (int t = 0; t < NT; ++t) {
            __syncthreads();   // prev tile's compute done (and Q stage for t=0)
            #pragma unroll
            for (int it = 0; it < 4; ++it) {
                int r = it * 16 + (tid >> 5);
                int c = (tid & 31) * 4;
                *(float4*)&kt[r * LDQ + c] =
                    *(const float4*)(Kg + (size_t)(t * KT2 + r) * DD + c);
            }
            __syncthreads();

            float a0 = 0.f, a1 = 0.f, a2 = 0.f, a3 = 0.f;
            const float* kr = &kt[lane * LDQ];
            const float* qp0 = &qs[(4 * wv + 0) * LDQ];
            const float* qp1 = &qs[(4 * wv + 1) * LDQ];
            const float* qp2 = &qs[(4 * wv + 2) * LDQ];
            const float* qp3 = &qs[(4 * wv + 3) * LDQ];
            #pragma unroll 8
            for (int d = 0; d < DKK; d += 4) {
                float4 kf = *(const float4*)(kr + d);
                float4 f0 = *(const float4*)(qp0 + d);
                float4 f1 = *(const float4*)(qp1 + d);
                float4 f2 = *(const float4*)(qp2 + d);
                float4 f3 = *(const float4*)(qp3 + d);
                a0 += f0.x * kf.x + f0.y * kf.y + f0.z * kf.z + f0.w * kf.w;
                a1 += f1.x * kf.x + f1.y * kf.y + f1.z * kf.z + f1.w * kf.w;
                a2 += f2.x * kf.x + f2.y * kf.y + f2.z * kf.z + f2.w * kf.w;
                a3 += f3.x * kf.x + f3.y * kf.y + f3.z * kf.z + f3.w * kf.w;
            }
            uv[0][t] = f2u_ord(a0 * SCALE);
            uv[1][t] = f2u_ord(a1 * SCALE);
            uv[2][t] = f2u_ord(a2 * SCALE);
            uv[3][t] = f2u_ord(a3 * SCALE);
        }
    }

    // --- selection + softmax params per row (round-3 verified logic) ---
    unsigned pref[4];
    int ecnt[4];
    float mrow[4], invz[4], tvexp[4];
    #pragma unroll
    for (int r = 0; r < 4; ++r) {
        unsigned p = 0;
        for (int bit = 31; bit >= 0; --bit) {
            unsigned cand = p | (1u << bit);
            int cnt = 0;
            #pragma unroll
            for (int t = 0; t < NT; ++t)
                cnt += __popcll(__ballot(uv[r][t] >= cand));
            if (cnt >= KKTOP) p = cand;
        }
        pref[r] = p;
        int g = 0;
        #pragma unroll
        for (int t = 0; t < NT; ++t)
            g += __popcll(__ballot(uv[r][t] > p));
        ecnt[r] = KKTOP - g;

        unsigned um = 0;
        #pragma unroll
        for (int t = 0; t < NT; ++t) um = um > uv[r][t] ? um : uv[r][t];
        #pragma unroll
        for (int o = 32; o > 0; o >>= 1) {
            unsigned tv = __shfl_down(um, o);
            um = um > tv ? um : tv;
        }
        um = __shfl(um, 0);
        const float m = u2f_ord(um);

        float se = 0.f;
        #pragma unroll
        for (int t = 0; t < NT; ++t)
            if (uv[r][t] > p) se += expf(u2f_ord(uv[r][t]) - m);
        #pragma unroll
        for (int o = 32; o > 0; o >>= 1) se += __shfl_down(se, o);
        se = __shfl(se, 0);

        mrow[r] = m;
        tvexp[r] = expf(u2f_ord(p) - m);
        invz[r] = 1.0f / (se + (float)ecnt[r] * tvexp[r]);
    }

    // --- weights (in-register, uv overwritten in place) + attn write ---
    #pragma unroll
    for (int r = 0; r < 4; ++r) {
        float* ao = attn_out +
            ((size_t)((b * HH + h) * SS + q0 + 4 * wv + r)) * SS;
        int tiesbefore = 0;
        #pragma unroll
        for (int t = 0; t < NT; ++t) {
            const unsigned u = uv[r][t];
            const bool eq = (u == pref[r]);
            unsigned long long mask = __ballot(eq);
            float w;
            if (u > pref[r]) {
                w = expf(u2f_ord(u) - mrow[r]) * invz[r];
            } else if (eq) {
                int rank = tiesbefore + __popcll(mask & ((1ull << lane) - 1ull));
                w = (rank < ecnt[r]) ? tvexp[r] * invz[r] : 0.f;
            } else {
                w = 0.f;
            }
            uv[r][t] = __float_as_uint(w);
            ao[t * 64 + lane] = w;
            tiesbefore += __popcll(mask);
        }
    }

    // --- PV: ctx[32][128] = W[32][1024] @ V[1024][128], tiled ---
    float* wt = lds + QS_OFF;   // wtile [32][64]  (qs is dead)
    float* vt = lds + KT_OFF;   // vtile [64][132]
    const int d = tid & 127;
    const int rq = tid >> 7;    // rows rq*8 .. rq*8+7
    float acc2[8];
    #pragma unroll
    for (int i = 0; i < 8; ++i) acc2[i] = 0.f;

    const float* Vg = V + (size_t)b * SS * DD + h * DKK;
    for (int t = 0; t < NT; ++t) {
        __syncthreads();   // prev tile compute done / scores-phase reads done
        #pragma unroll
        for (int it = 0; it < 4; ++it) {
            int r = it * 16 + (tid >> 5);
            int c = (tid & 31) * 4;
            *(float4*)&vt[r * LDQ + c] =
                *(const float4*)(Vg + (size_t)(t * KT2 + r) * DD + c);
        }
        #pragma unroll
        for (int r = 0; r < 4; ++r)
            wt[(4 * wv + r) * 64 + lane] = __uint_as_float(uv[r][t]);
        __syncthreads();

        #pragma unroll 4
        for (int jg = 0; jg < KT2; jg += 4) {
            float4 wrow[8];
            #pragma unroll
            for (int i = 0; i < 8; ++i)
                wrow[i] = *(const float4*)&wt[(rq * 8 + i) * 64 + jg];
            float v0 = vt[(jg + 0) * LDQ + d];
            float v1 = vt[(jg + 1) * LDQ + d];
            float v2 = vt[(jg + 2) * LDQ + d];
            float v3 = vt[(jg + 3) * LDQ + d];
            #pragma unroll
            for (int i = 0; i < 8; ++i)
                acc2[i] += wrow[i].x * v0 + wrow[i].y * v1 +
                           wrow[i].z * v2 + wrow[i].w * v3;
        }
    }

    {
        float* cb = CTX + (size_t)(b * SS + q0 + rq * 8) * DD + h * DKK + d;
        #pragma unroll
        for (int i = 0; i < 8; ++i)
            cb[(size_t)i * DD] = acc2[i];
    }
}

// ---------------------------------------------------------------------------
extern "C" void kernel_launch(void* const* d_in, const int* in_sizes, int n_in,
                              void* d_out, int out_size, void* d_ws, size_t ws_size,
                              hipStream_t stream)
{
    const float* x  = (const float*)d_in[0];
    const float* Wq = (const float*)d_in[1];
    const float* bq = (const float*)d_in[2];
    const float* Wk = (const float*)d_in[3];
    const float* bk = (const float*)d_in[4];
    const float* Wv = (const float*)d_in[5];
    const float* bv = (const float*)d_in[6];
    const float* Wo = (const float*)d_in[7];
    const float* bo = (const float*)d_in[8];

    float* out      = (float*)d_out;                       // [4,1024,2048]
    float* attn_out = (float*)d_out + (size_t)MROWS * DD;  // [4,16,1024,1024]

    float* ws = (float*)d_ws;
    const size_t PLANE = (size_t)MROWS * DD;
    float* Qb  = ws;
    float* Kb  = ws + PLANE;
    float* Vb  = ws + 2 * PLANE;
    float* CTX = ws + 3 * PLANE;

    dim3 gb(MROWS / TM, DD / TN);
    gemm_nt_f32<<<gb, 256, 0, stream>>>(x, Wq, bq, Qb, MROWS, DD, DD);
    gemm_nt_f32<<<gb, 256, 0, stream>>>(x, Wk, bk, Kb, MROWS, DD, DD);
    gemm_nt_f32<<<gb, 256, 0, stream>>>(x, Wv, bv, Vb, MROWS, DD, DD);

    attn_topk_fused<<<dim3(SS / QB, HH, BB), 512, 0, stream>>>(
        Qb, Kb, Vb, attn_out, CTX);

    gemm_nt_f32<<<gb, 256, 0, stream>>>(CTX, Wo, bo, out, MROWS, DD, DD);
}